// Round 3
// baseline (1691.995 us; speedup 1.0000x reference)
//
#include <hip/hip_runtime.h>
#include <math.h>

#define ACT_NONE 0
#define ACT_ELU  1
#define ACT_TANH 2

__device__ __forceinline__ float eluf(float v) { return v > 0.f ? v : __expf(v) - 1.f; }

// ---------------------------------------------------------------------------
// fp32 vector GEMM: C[M,N] = act(A @ B + bias)
// A: fp32 [M, lda] row-major (lda multiple of 4), B: fp32 [Kb, ldb] row-major
// (rows k >= Kb read as zero). 128x128 block tile, BK=16, 256 threads,
// 8x8 per thread. K and kChunk must be multiples of 16.
// ATOMIC=true: fp32 atomicAdd into C (split-K via blockIdx.z), no bias/act.
// ---------------------------------------------------------------------------
template <int ACT, bool ATOMIC>
__global__ __launch_bounds__(256) void fgemm(
    const float* __restrict__ A, int lda,
    const float* __restrict__ B, int ldb, int Kb,
    const float* __restrict__ bias,
    float* __restrict__ C, int ldc,
    int M, int N, int K, int kChunk)
{
    __shared__ float As[16][132];   // [k][m], +4 pad (2-way max on writes: free)
    __shared__ float Bs[16][128];   // [k][n]

    const int tid = threadIdx.x;
    const int tx = tid & 15;        // col group
    const int ty = tid >> 4;        // row group
    const int m0 = blockIdx.y * 128;
    const int n0 = blockIdx.x * 128;
    const int kbeg = blockIdx.z * kChunk;
    const int kend = min(K, kbeg + kChunk);

    float acc[8][8];
#pragma unroll
    for (int i = 0; i < 8; ++i)
#pragma unroll
        for (int j = 0; j < 8; ++j) acc[i][j] = 0.f;

    for (int k0 = kbeg; k0 < kend; k0 += 16) {
        // ---- stage A (128 rows x 16 k), transposed into As[k][m] ----
        {
            int row = tid >> 1;              // 0..127
            int kq  = (tid & 1) * 8;         // 0 or 8
            int gm  = m0 + row;
            float4 v0 = {0.f,0.f,0.f,0.f}, v1 = {0.f,0.f,0.f,0.f};
            if (gm < M) {
                const float* p = A + (size_t)gm * lda + k0 + kq;
                v0 = *reinterpret_cast<const float4*>(p);
                v1 = *reinterpret_cast<const float4*>(p + 4);
            }
            As[kq + 0][row] = v0.x; As[kq + 1][row] = v0.y;
            As[kq + 2][row] = v0.z; As[kq + 3][row] = v0.w;
            As[kq + 4][row] = v1.x; As[kq + 5][row] = v1.y;
            As[kq + 6][row] = v1.z; As[kq + 7][row] = v1.w;
        }
        // ---- stage B (16 k x 128 n) into Bs[k][n] ----
        {
            int kr = tid >> 4;               // 0..15
            int nc = (tid & 15) * 8;         // 0,8,..,120
            int gk = k0 + kr;
            float4 v0 = {0.f,0.f,0.f,0.f}, v1 = {0.f,0.f,0.f,0.f};
            if (gk < Kb) {
                const float* p = B + (size_t)gk * ldb + n0 + nc;
                if (n0 + nc + 7 < N) {
                    v0 = *reinterpret_cast<const float4*>(p);
                    v1 = *reinterpret_cast<const float4*>(p + 4);
                } else {
                    float t[8];
#pragma unroll
                    for (int i = 0; i < 8; ++i) t[i] = (n0 + nc + i < N) ? p[i] : 0.f;
                    v0 = {t[0],t[1],t[2],t[3]}; v1 = {t[4],t[5],t[6],t[7]};
                }
            }
            *reinterpret_cast<float4*>(&Bs[kr][nc])     = v0;
            *reinterpret_cast<float4*>(&Bs[kr][nc + 4]) = v1;
        }
        __syncthreads();

#pragma unroll
        for (int k = 0; k < 16; ++k) {
            float a[8], b[8];
#pragma unroll
            for (int i = 0; i < 8; ++i) a[i] = As[k][ty * 8 + i];
#pragma unroll
            for (int j = 0; j < 8; ++j) b[j] = Bs[k][tx * 8 + j];
#pragma unroll
            for (int i = 0; i < 8; ++i)
#pragma unroll
                for (int j = 0; j < 8; ++j) acc[i][j] = fmaf(a[i], b[j], acc[i][j]);
        }
        __syncthreads();
    }

    // ---- epilogue ----
#pragma unroll
    for (int i = 0; i < 8; ++i) {
        int row = m0 + ty * 8 + i;
        if (row >= M) continue;
#pragma unroll
        for (int j = 0; j < 8; ++j) {
            int col = n0 + tx * 8 + j;
            if (col >= N) continue;
            float v = acc[i][j];
            if (ATOMIC) {
                atomicAdd(&C[(size_t)row * ldc + col], v);
            } else {
                v += bias[col];
                if (ACT == ACT_TANH) v = tanhf(v);
                else if (ACT == ACT_ELU) v = eluf(v);
                C[(size_t)row * ldc + col] = v;
            }
        }
    }
}

// ---------------------------------------------------------------------------
__global__ __launch_bounds__(256) void zero_f32(float* __restrict__ p, int n)
{
    int i = blockIdx.x * 256 + threadIdx.x;
    if (i < n) p[i] = 0.f;
}

__global__ __launch_bounds__(256) void bias_elu_inplace(
    float* __restrict__ p, const float* __restrict__ bias, int n, int N)
{
    int i = blockIdx.x * 256 + threadIdx.x;
    if (i < n) p[i] = eluf(p[i] + bias[i % N]);
}

// ---------------------------------------------------------------------------
// Row-per-block GEMM for small N/K: out[m,:] = act(A[m,:] @ W + bias)
// All fp32. W [K,N] row-major (fits in L2; lane-coalesced column reads).
// Pads cols [N, padWidth) with zeros.
// ---------------------------------------------------------------------------
template <int ACT>
__global__ __launch_bounds__(256) void rowgemm(
    const float* __restrict__ A, int strideA,
    const float* __restrict__ W, const float* __restrict__ bias,
    float* __restrict__ out, int strideOut, int padWidth,
    int N, int K)
{
    __shared__ float Arow[928];
    const int m = blockIdx.x;
    const int t = threadIdx.x;
    for (int k = t; k < K; k += 256) Arow[k] = A[(size_t)m * strideA + k];
    __syncthreads();
    for (int n = t; n < padWidth; n += 256) {
        float s = 0.f;
        if (n < N) {
            s = bias[n];
            for (int k = 0; k < K; ++k) s = fmaf(Arow[k], W[(size_t)k * N + n], s);
            if (ACT == ACT_ELU) s = eluf(s);
        }
        out[(size_t)m * strideOut + n] = s;
    }
}

// ---------------------------------------------------------------------------
// Latent: Bmat = W .* relu(j-i); eps = exp(logvar/2)*noise;
// z = forward substitution of z(I-B)=eps; Bz = z@Bmat. All fp32.
// Writes outputs z / logvar / Bz / Bmat and z to ws for the decoder.
// ---------------------------------------------------------------------------
__global__ __launch_bounds__(256) void latent_kernel(
    const float* __restrict__ logvar,
    const float* __restrict__ eps_noise,
    const float* __restrict__ Wlat,
    float* __restrict__ z_ws,
    float* __restrict__ out)
{
    __shared__ float Bm[256];
    const int t = threadIdx.x;
    {
        int i = t >> 4, j = t & 15;
        float v = (j > i) ? Wlat[t] * (float)(j - i) : 0.f;
        Bm[t] = v;
        if (blockIdx.x == 0) out[49152 + t] = v;        // Bmat
    }
    __syncthreads();

    const int b = blockIdx.x * 256 + t;
    float lv[16], z[16];
#pragma unroll
    for (int j = 0; j < 16; ++j) lv[j] = logvar[b * 16 + j];
#pragma unroll
    for (int j = 0; j < 16; ++j) {
        float s = __expf(0.5f * fminf(lv[j], 80.f)) * eps_noise[b * 16 + j];
        for (int i = 0; i < j; ++i) s = fmaf(z[i], Bm[i * 16 + j], s);
        z[j] = s;
    }
#pragma unroll
    for (int j = 0; j < 16; ++j) {
        float bz = 0.f;
#pragma unroll
        for (int i = 0; i < 16; ++i) bz = fmaf(z[i], Bm[i * 16 + j], bz);
        out[b * 16 + j]         = z[j];
        out[16384 + b * 16 + j] = lv[j];
        out[32768 + b * 16 + j] = bz;
        z_ws[b * 16 + j] = z[j];
    }
}

// ---------------------------------------------------------------------------
// Workspace (fp32, 7.52 MB total):
//   h1 [1024,900] @ 0          h2 [1024,300] @ 3,686,400
//   lv [1024,16]  @ 4,915,200  zf [1024,16]  @ 4,980,736
//   g1 [1024,300] @ 5,046,272  g2 [1024,304] @ 6,275,072 (cols 300..303 = 0)
// Output (fp32 flat): z[16384] | logvar[16384] | Bz[16384] | Bmat[256] |
//                     xhat[28311552]
// ---------------------------------------------------------------------------
extern "C" void kernel_launch(void* const* d_in, const int* in_sizes, int n_in,
                              void* d_out, int out_size, void* d_ws, size_t ws_size,
                              hipStream_t stream)
{
    const float* x       = (const float*)d_in[0];   // [1024, 27648]
    const float* eps_n   = (const float*)d_in[1];   // [1024, 16]
    const float* enc_w1  = (const float*)d_in[2];   // [27648, 900]
    const float* enc_b1  = (const float*)d_in[3];
    const float* enc_w2  = (const float*)d_in[4];   // [900, 300]
    const float* enc_b2  = (const float*)d_in[5];
    const float* lv_w    = (const float*)d_in[6];   // [300, 16]
    const float* lv_b    = (const float*)d_in[7];
    const float* Wlat    = (const float*)d_in[8];   // [16, 16]
    const float* dec_w1  = (const float*)d_in[9];   // [16, 300]
    const float* dec_b1  = (const float*)d_in[10];
    const float* dec_w2  = (const float*)d_in[11];  // [300, 300]
    const float* dec_b2  = (const float*)d_in[12];
    const float* dec_w3  = (const float*)d_in[13];  // [300, 27648]
    const float* dec_b3  = (const float*)d_in[14];

    char* ws = (char*)d_ws;
    float* h1 = (float*)(ws + 0);
    float* h2 = (float*)(ws + 3686400);
    float* lv = (float*)(ws + 4915200);
    float* zf = (float*)(ws + 4980736);
    float* g1 = (float*)(ws + 5046272);
    float* g2 = (float*)(ws + 6275072);

    float* out = (float*)d_out;

    // 0) zero split-K accumulator
    zero_f32<<<3600, 256, 0, stream>>>(h1, 921600);

    // 1) h1 += x @ enc_w1  (split-K=8, fp32 atomics; kChunk 3456 = 27648/8)
    fgemm<ACT_NONE, true><<<dim3(8, 8, 8), 256, 0, stream>>>(
        x, 27648, enc_w1, 900, 27648, nullptr,
        h1, 900, 1024, 900, 27648, 3456);

    // 2) h1 = elu(h1 + enc_b1)
    bias_elu_inplace<<<3600, 256, 0, stream>>>(h1, enc_b1, 921600, 900);

    // 3) h2 = elu(h1 @ enc_w2 + enc_b2)
    rowgemm<ACT_ELU><<<1024, 256, 0, stream>>>(
        h1, 900, enc_w2, enc_b2, h2, 300, 300, 300, 900);

    // 4) logvar = h2 @ lv_w + lv_b
    rowgemm<ACT_NONE><<<1024, 256, 0, stream>>>(
        h2, 300, lv_w, lv_b, lv, 16, 16, 16, 300);

    // 5) latent: z / logvar / Bz / Bmat outputs + fp32 z scratch
    latent_kernel<<<4, 256, 0, stream>>>(lv, eps_n, Wlat, zf, out);

    // 6) g1 = elu(z @ dec_w1 + dec_b1)
    rowgemm<ACT_ELU><<<1024, 256, 0, stream>>>(
        zf, 16, dec_w1, dec_b1, g1, 300, 300, 300, 16);

    // 7) g2 = elu(g1 @ dec_w2 + dec_b2), stride 304, cols 300..303 zeroed
    rowgemm<ACT_ELU><<<1024, 256, 0, stream>>>(
        g1, 300, dec_w2, dec_b2, g2, 304, 304, 300, 300);

    // 8) xhat = tanh(g2 @ dec_w3 + dec_b3)  (K=304 incl. pad; B k-guard 300)
    fgemm<ACT_TANH, false><<<dim3(216, 8, 1), 256, 0, stream>>>(
        g2, 304, dec_w3, 27648, 300, dec_b3,
        out + 49408, 27648, 1024, 27648, 304, 304);
}